// Round 15
// baseline (178.945 us; speedup 1.0000x reference)
//
#include <hip/hip_runtime.h>
#include <hip/hip_bf16.h>

typedef unsigned short u16;
typedef unsigned int u32;
typedef __attribute__((ext_vector_type(8))) short short8;
typedef __attribute__((ext_vector_type(4))) float f32x4;
typedef __attribute__((ext_vector_type(4))) u16 us4;

#define MFMA16(a,b,c) __builtin_amdgcn_mfma_f32_16x16x32_bf16(a,b,c,0,0,0)

__device__ __forceinline__ u16 f2b(float x){
  u32 u = __builtin_bit_cast(u32, x);
  u32 r = (u + 0x7fffu + ((u >> 16) & 1u)) >> 16;
  return (u16)r;
}
__device__ __forceinline__ u16 f2b_hw(float x){
  return __builtin_bit_cast(u16, __float2bfloat16(x));
}
__device__ __forceinline__ float ex2(float x){ return __builtin_amdgcn_exp2f(x); }
__device__ __forceinline__ float b2f(u16 v){ return __builtin_bit_cast(float, ((u32)v) << 16); }

__device__ __forceinline__ void gll16(const u16* g, u16* l){
  __builtin_amdgcn_global_load_lds((const __attribute__((address_space(1))) u32*)g,
                                   (__attribute__((address_space(3))) u32*)l, 16, 0, 0);
}

// ---------------- fused: f32->bf16 convert (Drift+Ocean) + weight transposes + lambda ----------
__global__ __launch_bounds__(256) void k_prep(const float* __restrict__ Drift, const float* __restrict__ Ocean,
                                              const float* __restrict__ Wq, const float* __restrict__ Wk,
                                              const float* __restrict__ Wv, const float* __restrict__ Wo,
                                              u16* __restrict__ Xd, u16* __restrict__ Xo,
                                              u16* __restrict__ WqT, u16* __restrict__ WkvT,
                                              u16* __restrict__ WoT,
                                              const float* __restrict__ lq1, const float* __restrict__ lk1,
                                              const float* __restrict__ lq2, const float* __restrict__ lk2,
                                              float* __restrict__ lam){
  __shared__ float t[32][33];
  int bid = blockIdx.x;
  if (bid < 8192){
    const float* x = (bid < 4096) ? Drift : Ocean;
    u16* y = (bid < 4096) ? Xd : Xo;
    int i = (bid & 4095) * 256 + threadIdx.x;
    float4 v = reinterpret_cast<const float4*>(x)[i];
    us4 o; o.x = f2b(v.x); o.y = f2b(v.y); o.z = f2b(v.z); o.w = f2b(v.w);
    reinterpret_cast<us4*>(y)[i] = o;
    return;
  }
  int tt = bid - 8192;
  int z = tt >> 11;
  int bx = tt & 63, by = (tt & 2047) >> 6;
  const float* W; u16* WT; int N; float scale = 1.0f;
  if (z == 0){ W = Wq; WT = WqT; N = 2048; scale = 0.1803368867f; }   // 0.125 * log2(e)
  else if (z == 1){ W = Wk; WT = WkvT; N = 2048; }
  else if (z == 2){ W = Wv; WT = WkvT + 2048*1024; N = 1024; }
  else { W = Wo; WT = WoT; N = 1024; }
  int n0 = bx * 32, k0 = by * 32;
  int tx = threadIdx.x & 31, ty = threadIdx.x >> 5;
  if (n0 < N){
    #pragma unroll
    for (int i = 0; i < 4; i++)
      t[ty + i*8][tx] = W[(size_t)(k0 + ty + i*8) * N + n0 + tx];
    __syncthreads();
    #pragma unroll
    for (int i = 0; i < 4; i++)
      WT[(size_t)(n0 + ty + i*8) * 1024 + k0 + tx] = f2b(t[tx][ty + i*8] * scale);
  }
  if (z == 3 && bx == 0 && by == 0 && threadIdx.x < 16){
    int h = threadIdx.x;
    float d1 = 0.f, d2 = 0.f;
    for (int i = 0; i < 64; i++){
      d1 += lq1[h*64 + i] * lk1[h*64 + i];
      d2 += lq2[h*64 + i] * lk2[h*64 + i];
    }
    lam[h] = expf(d1) - expf(d2) + 0.1f;
  }
}

// ---------------- V slice of KVb -> VT [64 bh][64 d][1024 kv] bf16 ----------------
__global__ __launch_bounds__(256) void k_transpose_v(const u16* __restrict__ KV, u16* __restrict__ VT){
  __shared__ u16 t[32][34];
  int kv0 = blockIdx.x * 32, d0 = blockIdx.y * 32, bh = blockIdx.z;
  int b = bh >> 4, h = bh & 15;
  int tx = threadIdx.x & 31, ty = threadIdx.x >> 5;
  #pragma unroll
  for (int i = 0; i < 4; i++)
    t[ty + i*8][tx] = KV[(size_t)(b*1024 + kv0 + ty + i*8) * 3072 + 2048 + h*64 + d0 + tx];
  __syncthreads();
  #pragma unroll
  for (int i = 0; i < 4; i++)
    VT[(size_t)bh * 65536 + (size_t)(d0 + ty + i*8) * 1024 + kv0 + tx] = t[tx][ty + i*8];
}

// ---------------- GEMM body: 128x128 tile, BK=64, K=1024, 3-ring + counted vmcnt ----------------
// R12-attn's proven pipeline pattern: stage t+2 while computing t; end-of-step vmcnt(8)
// (t+1's 8 loads complete, t+2's 8 stay in flight) + ONE s_barrier. LDS 48KB -> 3 blocks/CU.
template<bool OUTF32>
__device__ __forceinline__ void gemm_body(const u16* __restrict__ A, const u16* __restrict__ B,
                                          void* __restrict__ C, int N, int m0, int n0,
                                          u16* As, u16* Bs){
  const int tid = threadIdx.x;
  const int wave = tid >> 6, lane = tid & 63;
  const int lr = lane & 15, lg = lane >> 4;
  const int wm = wave >> 1, wn = wave & 1;
  const int srow = tid >> 3, skc = tid & 7;

  f32x4 acc[4][4];
  #pragma unroll
  for (int i = 0; i < 4; i++)
    #pragma unroll
    for (int j = 0; j < 4; j++){ f32x4 z = {0.f,0.f,0.f,0.f}; acc[i][j] = z; }

  auto STAGE = [&](int buf, int t){
    const int k0 = t << 6;
    #pragma unroll
    for (int c = 0; c < 4; c++){
      int row = c*32 + srow;
      const u16* ga = A + (size_t)(m0 + row) * 1024 + k0 + ((skc ^ (row & 7)) << 3);
      gll16(ga, As + buf*4096 + c*1024 + wave*256 + (tid & 63)*0 + (tid - wave*64)*0 + ( (tid & 63) * 8 ) - ((tid & 63) * 8) + ( ( (tid & 63) ) * 8 ));
      // NOTE: dest must be linear per-wave: simplify below
    }
  };
  (void)STAGE;

  // linear LDS dest (same layout as R12): slot base + c*2048 + wave*512 (u16 units)
  auto STAGE2 = [&](int buf, int t){
    const int k0 = t << 6;
    #pragma unroll
    for (int c = 0; c < 4; c++){
      int row = c*32 + srow;
      const u16* ga = A + (size_t)(m0 + row) * 1024 + k0 + ((skc ^ (row & 7)) << 3);
      gll16(ga, As + buf*8192 + c*2048 + wave*512);
      const u16* gb = B + (size_t)(n0 + row) * 1024 + k0 + ((skc ^ (row & 7)) << 3);
      gll16(gb, Bs + buf*8192 + c*2048 + wave*512);
    }
  };

  // prologue: stage tiles 0,1; wait tile0 (8 outstanding = tile1's)
  STAGE2(0, 0);
  STAGE2(1, 1);
  asm volatile("s_waitcnt vmcnt(8)" ::: "memory");
  __builtin_amdgcn_s_barrier();
  __builtin_amdgcn_sched_barrier(0);

  for (int t = 0; t < 16; t++){
    const int cur = t % 3;
    if (t <= 13) STAGE2((t + 2) % 3, t + 2);           // stage t+2 into freed ring slot

    const u16* as = As + cur*8192;
    const u16* bs = Bs + cur*8192;
    #pragma unroll
    for (int kc = 0; kc < 2; kc++){
      short8 af[4], bfr[4];
      #pragma unroll
      for (int mt = 0; mt < 4; mt++){
        int row = wm*64 + mt*16 + lr;
        af[mt] = *reinterpret_cast<const short8*>(as + row*64 + (((kc*4 + lg) ^ (row & 7)) << 3));
      }
      #pragma unroll
      for (int nt = 0; nt < 4; nt++){
        int rown = wn*64 + nt*16 + lr;
        bfr[nt] = *reinterpret_cast<const short8*>(bs + rown*64 + (((kc*4 + lg) ^ (rown & 7)) << 3));
      }
      __builtin_amdgcn_s_setprio(1);
      #pragma unroll
      for (int mt = 0; mt < 4; mt++)
        #pragma unroll
        for (int nt = 0; nt < 4; nt++)
          acc[mt][nt] = MFMA16(af[mt], bfr[nt], acc[mt][nt]);
      __builtin_amdgcn_s_setprio(0);
    }

    if (t <= 13){
      asm volatile("s_waitcnt vmcnt(8)" ::: "memory"); // t+1 complete; t+2 stays in flight
      __builtin_amdgcn_s_barrier();
      __builtin_amdgcn_sched_barrier(0);
    } else if (t == 14){
      asm volatile("s_waitcnt vmcnt(0)" ::: "memory");
      __builtin_amdgcn_s_barrier();
      __builtin_amdgcn_sched_barrier(0);
    }
  }
  #pragma unroll
  for (int mt = 0; mt < 4; mt++)
    #pragma unroll
    for (int nt = 0; nt < 4; nt++)
      #pragma unroll
      for (int r = 0; r < 4; r++){
        int row = m0 + wm*64 + mt*16 + lg*4 + r;
        int col = n0 + wn*64 + nt*16 + lr;
        if (OUTF32) ((float*)C)[(size_t)row * N + col] = acc[mt][nt][r];
        else        ((u16*)C)[(size_t)row * N + col] = f2b(acc[mt][nt][r]);
      }
}

// fused projection GEMM with XCD-chunked swizzle (1280 % 8 == 0, bijective)
__global__ __launch_bounds__(256) void k_gemm_proj(const u16* __restrict__ Xd, const u16* __restrict__ Xo,
                                                   const u16* __restrict__ WqT, const u16* __restrict__ WkvT,
                                                   u16* __restrict__ Qb, u16* __restrict__ KVb){
  __shared__ __align__(16) u16 As[3*8192];   // 48KB ring (A 24 + B 24)
  __shared__ __align__(16) u16 Bs[3*8192];
  int bid0 = blockIdx.x;
  int bid = (bid0 & 7) * 160 + (bid0 >> 3);
  if (bid < 512){
    gemm_body<false>(Xd, WqT, Qb, 2048, (bid >> 4) * 128, (bid & 15) * 128, As, Bs);
  } else {
    int t = bid - 512;
    gemm_body<false>(Xo, WkvT, KVb, 3072, (t / 24) * 128, (t % 24) * 128, As, Bs);
  }
}

// output GEMM: out = Ob * WoT^T, f32 out
__global__ __launch_bounds__(256) void k_gemm_out(const u16* __restrict__ A, const u16* __restrict__ B,
                                                  float* __restrict__ C){
  __shared__ __align__(16) u16 As[3*8192];
  __shared__ __align__(16) u16 Bs[3*8192];
  int bid = blockIdx.x;
  gemm_body<true>(A, B, C, 1024, (bid >> 3) * 128, (bid & 7) * 128, As, Bs);
}

// ---------------- no-max softmax on S^T, exp2 domain (lane q = lr) ----------------
__device__ __forceinline__ void softmax_t(f32x4 s[4], float& l, u16* pl, int lr, int lg, int swzv){
  float sum = 0.f;
  #pragma unroll
  for (int nt = 0; nt < 4; nt++)
    #pragma unroll
    for (int r = 0; r < 4; r++){
      float p = ex2(s[nt][r]);
      s[nt][r] = p;
      sum += p;
    }
  sum += __shfl_xor(sum, 16);
  sum += __shfl_xor(sum, 32);
  l += sum;
  char* base = (char*)pl + lr * 128;
  #pragma unroll
  for (int nt = 0; nt < 4; nt++){
    us4 h;
    h.x = f2b_hw(s[nt][0]); h.y = f2b_hw(s[nt][1]);
    h.z = f2b_hw(s[nt][2]); h.w = f2b_hw(s[nt][3]);
    *reinterpret_cast<us4*>(base + ((nt*32 + lg*8) ^ (swzv << 4))) = h;
  }
}

// ---------------- differential flash attention: branch-per-wave, 3-buf ring, counted vmcnt ----
__global__ __launch_bounds__(512) void k_attn(const u16* __restrict__ Q, const u16* __restrict__ KVb,
                                              const u16* __restrict__ VT, const float* __restrict__ lam,
                                              u16* __restrict__ O){
  int bid = blockIdx.x;
  int logical = (bid & 7) * 32 + (bid >> 3);           // 256 % 8 == 0, bijective
  int qt2 = logical & 3, h = (logical >> 2) & 15, b = logical >> 6;
  const int tid = threadIdx.x, wave = tid >> 6, lane = tid & 63;
  const int lr = lane & 15, lg = lane >> 4;
  const int br = wave >> 2, wq = wave & 3;             // branch, q-slot
  const int swzv = (lr ^ (lr >> 3)) & 7;

  __shared__ __align__(16) u16 Ks[3][8192];            // ring [buf][64 kv][128 d] chunk-swizzled
  __shared__ __align__(16) u16 Vs[3][4096];            // ring [buf][64 d][64 kv] chunk-swizzled
  __shared__ __align__(16) u16 Pl[8][4][1024];         // [wave][qt][16 q][64 kv]; reused for combine

  const int srow = tid >> 4, schunk = tid & 15;
  const int vrow = tid >> 3, vchunk = tid & 7;
  const u16* Kg = KVb + (size_t)(b*1024 + srow) * 3072 + h*128 + ((schunk ^ (srow & 7)) << 3);
  const u16* Vg = VT + (size_t)(b*16 + h) * 65536 + (size_t)vrow * 1024 + ((vchunk ^ (vrow & 7)) << 3);

  short8 qf[4][2];
  #pragma unroll
  for (int qt = 0; qt < 4; qt++){
    const u16* Qp = Q + (size_t)(b*1024 + qt2*256 + wq*64 + qt*16 + lr) * 2048 + h*128 + br*64 + lg*8;
    qf[qt][0] = *reinterpret_cast<const short8*>(Qp);
    qf[qt][1] = *reinterpret_cast<const short8*>(Qp + 32);
  }
  const float lamh = lam[h];

  f32x4 o[4][4];
  #pragma unroll
  for (int nt = 0; nt < 4; nt++)
    #pragma unroll
    for (int qt = 0; qt < 4; qt++){ f32x4 z = {0.f,0.f,0.f,0.f}; o[nt][qt] = z; }
  float l[4] = {0.f, 0.f, 0.f, 0.f};

  auto STAGE = [&](int buf, int kv0){
    #pragma unroll
    for (int i = 0; i < 2; i++)
      gll16(Kg + (size_t)(kv0 + i*32) * 3072, &Ks[buf][i*4096 + tid*8]);
    gll16(Vg + kv0, &Vs[buf][tid*8]);
  };

  STAGE(0, 0);
  STAGE(1, 64);
  asm volatile("s_waitcnt vmcnt(3)" ::: "memory");
  __builtin_amdgcn_s_barrier();
  __builtin_amdgcn_sched_barrier(0);

  u16* Plw = &Pl[wave][0][0];

  for (int t = 0; t < 16; t++){
    const int cur = t % 3;
    if (t <= 13) STAGE((t + 2) % 3, (t + 2) << 6);

    const u16* kbuf = &Ks[cur][0];
    const u16* vbuf = &Vs[cur][0];

    short8 kf[4][2];
    #pragma unroll
    for (int nt = 0; nt < 4; nt++)
      #pragma unroll
      for (int kc = 0; kc < 2; kc++)
        kf[nt][kc] = *reinterpret_cast<const short8*>(
            kbuf + (nt*16 + lr)*128 + (((br*8 + kc*4 + lg) ^ (lr & 7)) << 3));
    #pragma unroll
    for (int qt = 0; qt < 4; qt++){
      f32x4 s[4];
      #pragma unroll
      for (int nt = 0; nt < 4; nt++){ f32x4 z = {0.f,0.f,0.f,0.f}; s[nt] = z; }
      __builtin_amdgcn_s_setprio(1);
      #pragma unroll
      for (int nt = 0; nt < 4; nt++)
        #pragma unroll
        for (int kc = 0; kc < 2; kc++)
          s[nt] = MFMA16(kf[nt][kc], qf[qt][kc], s[nt]);
      __builtin_amdgcn_s_setprio(0);
      softmax_t(s, l[qt], Plw + qt*1024, lr, lg, swzv);
    }

    #pragma unroll
    for (int kc = 0; kc < 2; kc++){
      short8 pf[4];
      #pragma unroll
      for (int qt = 0; qt < 4; qt++)
        pf[qt] = *reinterpret_cast<const short8*>(
            (char*)(Plw + qt*1024) + lr*128 + ((kc*64 + lg*16) ^ (swzv << 4)));
      __builtin_amdgcn_s_setprio(1);
      #pragma unroll
      for (int nt = 0; nt < 4; nt++){
        short8 vf = *reinterpret_cast<const short8*>(
            vbuf + (nt*16 + lr)*64 + (((kc*4 + lg) ^ (lr & 7)) << 3));
        #pragma unroll
        for (int qt = 0; qt < 4; qt++)
          o[nt][qt] = MFMA16(vf, pf[qt], o[nt][qt]);
      }
      __builtin_amdgcn_s_setprio(0);
    }

    if (t <= 13){
      asm volatile("s_waitcnt vmcnt(3)" ::: "memory");
      __builtin_amdgcn_s_barrier();
      __builtin_amdgcn_sched_barrier(0);
    } else if (t == 14){
      asm volatile("s_waitcnt vmcnt(0)" ::: "memory");
      __builtin_amdgcn_s_barrier();
      __builtin_amdgcn_sched_barrier(0);
    }
  }

  if (br == 1){
    #pragma unroll
    for (int qt = 0; qt < 4; qt++){
      const float inv2 = lamh / l[qt];
      char* base = (char*)(Plw + qt*1024) + lr * 128;
      #pragma unroll
      for (int nt = 0; nt < 4; nt++){
        us4 hh;
        #pragma unroll
        for (int r = 0; r < 4; r++)
          ((u16*)&hh)[r] = f2b_hw(o[nt][qt][r] * inv2);
        *reinterpret_cast<us4*>(base + ((nt*32 + lg*8) ^ (swzv << 4))) = hh;
      }
    }
  }
  __syncthreads();
  if (br == 0){
    u16* Px = &Pl[wave + 4][0][0];
    #pragma unroll
    for (int qt = 0; qt < 4; qt++){
      const float inv1 = 1.0f / l[qt];
      char* base = (char*)(Px + qt*1024) + lr * 128;
      u16* Op = O + (size_t)(b*1024 + qt2*256 + wq*64 + qt*16 + lr) * 1024 + h*64;
      #pragma unroll
      for (int nt = 0; nt < 4; nt++){
        us4 x = *reinterpret_cast<const us4*>(base + ((nt*32 + lg*8) ^ (swzv << 4)));
        us4 hh;
        #pragma unroll
        for (int r = 0; r < 4; r++){
          float v = o[nt][qt][r] * inv1 - b2f(((const u16*)&x)[r]);
          ((u16*)&hh)[r] = f2b_hw(v);
        }
        *reinterpret_cast<us4*>(Op + nt*16 + lg*4) = hh;
      }
    }
  }
}

// ---------------- launch ----------------
extern "C" void kernel_launch(void* const* d_in, const int* in_sizes, int n_in,
                              void* d_out, int out_size, void* d_ws, size_t ws_size,
                              hipStream_t stream){
  const float* Drift = (const float*)d_in[0];
  const float* Ocean = (const float*)d_in[1];
  const float* Wq    = (const float*)d_in[2];
  const float* Wk    = (const float*)d_in[3];
  const float* Wv    = (const float*)d_in[4];
  const float* Wo    = (const float*)d_in[5];
  const float* lq1   = (const float*)d_in[6];
  const float* lk1   = (const float*)d_in[7];
  const float* lq2   = (const float*)d_in[8];
  const float* lk2   = (const float*)d_in[9];
  float* out = (float*)d_out;

  char* ws = (char*)d_ws;
  u16* Xd   = (u16*)(ws);                      // 4096x1024 bf16
  u16* Xo   = (u16*)(ws + 8388608);            // 4096x1024
  u16* WqT  = (u16*)(ws + 16777216);           // 2048x1024
  u16* WkvT = (u16*)(ws + 20971520);           // 3072x1024
  u16* WoT  = (u16*)(ws + 27262976);           // 1024x1024
  u16* Qb   = (u16*)(ws + 29360128);           // 4096x2048
  u16* KVb  = (u16*)(ws + 46137344);           // 4096x3072
  u16* VTb  = (u16*)(ws + 71303168);           // 64x64x1024
  u16* Ob   = (u16*)(ws + 79691776);           // 4096x1024
  float* lam = (float*)(ws + 88080384);        // 16 f32

  k_prep<<<16384, 256, 0, stream>>>(Drift, Ocean, Wq, Wk, Wv, Wo, Xd, Xo,
                                    WqT, WkvT, WoT, lq1, lk1, lq2, lk2, lam);
  k_gemm_proj<<<1280, 256, 0, stream>>>(Xd, Xo, WqT, WkvT, Qb, KVb);
  k_transpose_v<<<dim3(32,2,64), 256, 0, stream>>>(KVb, VTb);
  k_attn<<<256, 512, 0, stream>>>(Qb, KVb, VTb, lam, Ob);
  k_gemm_out<<<256, 256, 0, stream>>>(Ob, WoT, out);
}

// Round 16
// 141.803 us; speedup vs baseline: 1.2619x; 1.2619x over previous
//
#include <hip/hip_runtime.h>
#include <hip/hip_bf16.h>

typedef unsigned short u16;
typedef unsigned int u32;
typedef __attribute__((ext_vector_type(8))) short short8;
typedef __attribute__((ext_vector_type(4))) float f32x4;
typedef __attribute__((ext_vector_type(4))) u16 us4;

#define MFMA16(a,b,c) __builtin_amdgcn_mfma_f32_16x16x32_bf16(a,b,c,0,0,0)

__device__ __forceinline__ u16 f2b(float x){
  u32 u = __builtin_bit_cast(u32, x);
  u32 r = (u + 0x7fffu + ((u >> 16) & 1u)) >> 16;
  return (u16)r;
}
__device__ __forceinline__ u16 f2b_hw(float x){
  return __builtin_bit_cast(u16, __float2bfloat16(x));
}
__device__ __forceinline__ float ex2(float x){ return __builtin_amdgcn_exp2f(x); }
__device__ __forceinline__ float b2f(u16 v){ return __builtin_bit_cast(float, ((u32)v) << 16); }

__device__ __forceinline__ void gll16(const u16* g, u16* l){
  __builtin_amdgcn_global_load_lds((const __attribute__((address_space(1))) u32*)g,
                                   (__attribute__((address_space(3))) u32*)l, 16, 0, 0);
}

// ---------------- fused: f32->bf16 convert (Drift+Ocean) + weight transposes + lambda ----------
__global__ __launch_bounds__(256) void k_prep(const float* __restrict__ Drift, const float* __restrict__ Ocean,
                                              const float* __restrict__ Wq, const float* __restrict__ Wk,
                                              const float* __restrict__ Wv, const float* __restrict__ Wo,
                                              u16* __restrict__ Xd, u16* __restrict__ Xo,
                                              u16* __restrict__ WqT, u16* __restrict__ WkvT,
                                              u16* __restrict__ WoT,
                                              const float* __restrict__ lq1, const float* __restrict__ lk1,
                                              const float* __restrict__ lq2, const float* __restrict__ lk2,
                                              float* __restrict__ lam){
  __shared__ float t[32][33];
  int bid = blockIdx.x;
  if (bid < 8192){
    const float* x = (bid < 4096) ? Drift : Ocean;
    u16* y = (bid < 4096) ? Xd : Xo;
    int i = (bid & 4095) * 256 + threadIdx.x;
    float4 v = reinterpret_cast<const float4*>(x)[i];
    us4 o; o.x = f2b(v.x); o.y = f2b(v.y); o.z = f2b(v.z); o.w = f2b(v.w);
    reinterpret_cast<us4*>(y)[i] = o;
    return;
  }
  int tt = bid - 8192;
  int z = tt >> 11;
  int bx = tt & 63, by = (tt & 2047) >> 6;
  const float* W; u16* WT; int N; float scale = 1.0f;
  if (z == 0){ W = Wq; WT = WqT; N = 2048; scale = 0.1803368867f; }   // 0.125 * log2(e)
  else if (z == 1){ W = Wk; WT = WkvT; N = 2048; }
  else if (z == 2){ W = Wv; WT = WkvT + 2048*1024; N = 1024; }
  else { W = Wo; WT = WoT; N = 1024; }
  int n0 = bx * 32, k0 = by * 32;
  int tx = threadIdx.x & 31, ty = threadIdx.x >> 5;
  if (n0 < N){
    #pragma unroll
    for (int i = 0; i < 4; i++)
      t[ty + i*8][tx] = W[(size_t)(k0 + ty + i*8) * N + n0 + tx];
    __syncthreads();
    #pragma unroll
    for (int i = 0; i < 4; i++)
      WT[(size_t)(n0 + ty + i*8) * 1024 + k0 + tx] = f2b(t[tx][ty + i*8] * scale);
  }
  if (z == 3 && bx == 0 && by == 0 && threadIdx.x < 16){
    int h = threadIdx.x;
    float d1 = 0.f, d2 = 0.f;
    for (int i = 0; i < 64; i++){
      d1 += lq1[h*64 + i] * lk1[h*64 + i];
      d2 += lq2[h*64 + i] * lk2[h*64 + i];
    }
    lam[h] = expf(d1) - expf(d2) + 0.1f;
  }
}

// ---------------- V slice of KVb -> VT [64 bh][64 d][1024 kv] bf16 ----------------
__global__ __launch_bounds__(256) void k_transpose_v(const u16* __restrict__ KV, u16* __restrict__ VT){
  __shared__ u16 t[32][34];
  int kv0 = blockIdx.x * 32, d0 = blockIdx.y * 32, bh = blockIdx.z;
  int b = bh >> 4, h = bh & 15;
  int tx = threadIdx.x & 31, ty = threadIdx.x >> 5;
  #pragma unroll
  for (int i = 0; i < 4; i++)
    t[ty + i*8][tx] = KV[(size_t)(b*1024 + kv0 + ty + i*8) * 3072 + 2048 + h*64 + d0 + tx];
  __syncthreads();
  #pragma unroll
  for (int i = 0; i < 4; i++)
    VT[(size_t)bh * 65536 + (size_t)(d0 + ty + i*8) * 1024 + kv0 + tx] = t[tx][ty + i*8];
}

// ---------------- GEMM body (128x128 tile, BK=64, K=1024) — R8/R12-proven structure ----------------
template<bool OUTF32>
__device__ __forceinline__ void gemm_body(const u16* __restrict__ A, const u16* __restrict__ B,
                                          void* __restrict__ C, int N, int m0, int n0,
                                          u16* As, u16* Bs){
  const int tid = threadIdx.x;
  const int wave = tid >> 6, lane = tid & 63;
  const int lr = lane & 15, lg = lane >> 4;
  const int wm = wave >> 1, wn = wave & 1;

  f32x4 acc[4][4];
  #pragma unroll
  for (int i = 0; i < 4; i++)
    #pragma unroll
    for (int j = 0; j < 4; j++){ f32x4 z = {0.f,0.f,0.f,0.f}; acc[i][j] = z; }

  const int srow = tid >> 3;
  const int skc  = tid & 7;

  for (int k0 = 0; k0 < 1024; k0 += 64){
    #pragma unroll
    for (int c = 0; c < 4; c++){
      int row = c*32 + srow;
      const u16* ga = A + (size_t)(m0 + row) * 1024 + k0 + ((skc ^ (row & 7)) << 3);
      gll16(ga, As + c*2048 + wave*512);
      const u16* gb = B + (size_t)(n0 + row) * 1024 + k0 + ((skc ^ (row & 7)) << 3);
      gll16(gb, Bs + c*2048 + wave*512);
    }
    __syncthreads();
    #pragma unroll
    for (int kc = 0; kc < 2; kc++){
      short8 af[4], bfr[4];
      #pragma unroll
      for (int mt = 0; mt < 4; mt++){
        int row = wm*64 + mt*16 + lr;
        af[mt] = *reinterpret_cast<const short8*>(As + row*64 + (((kc*4 + lg) ^ (row & 7)) << 3));
      }
      #pragma unroll
      for (int nt = 0; nt < 4; nt++){
        int rown = wn*64 + nt*16 + lr;
        bfr[nt] = *reinterpret_cast<const short8*>(Bs + rown*64 + (((kc*4 + lg) ^ (rown & 7)) << 3));
      }
      #pragma unroll
      for (int mt = 0; mt < 4; mt++)
        #pragma unroll
        for (int nt = 0; nt < 4; nt++)
          acc[mt][nt] = MFMA16(af[mt], bfr[nt], acc[mt][nt]);
    }
    __syncthreads();
  }
  #pragma unroll
  for (int mt = 0; mt < 4; mt++)
    #pragma unroll
    for (int nt = 0; nt < 4; nt++)
      #pragma unroll
      for (int r = 0; r < 4; r++){
        int row = m0 + wm*64 + mt*16 + lg*4 + r;
        int col = n0 + wn*64 + nt*16 + lr;
        if (OUTF32) ((float*)C)[(size_t)row * N + col] = acc[mt][nt][r];
        else        ((u16*)C)[(size_t)row * N + col] = f2b(acc[mt][nt][r]);
      }
}

// fused projection GEMM with XCD-chunked swizzle (1280 % 8 == 0, bijective)
__global__ __launch_bounds__(256) void k_gemm_proj(const u16* __restrict__ Xd, const u16* __restrict__ Xo,
                                                   const u16* __restrict__ WqT, const u16* __restrict__ WkvT,
                                                   u16* __restrict__ Qb, u16* __restrict__ KVb){
  __shared__ __align__(16) u16 As[128*64];
  __shared__ __align__(16) u16 Bs[128*64];
  int bid0 = blockIdx.x;
  int bid = (bid0 & 7) * 160 + (bid0 >> 3);
  if (bid < 512){
    gemm_body<false>(Xd, WqT, Qb, 2048, (bid >> 4) * 128, (bid & 15) * 128, As, Bs);
  } else {
    int t = bid - 512;
    gemm_body<false>(Xo, WkvT, KVb, 3072, (t / 24) * 128, (t % 24) * 128, As, Bs);
  }
}

// output GEMM: out = Ob * WoT^T, f32 out
__global__ __launch_bounds__(256) void k_gemm_out(const u16* __restrict__ A, const u16* __restrict__ B,
                                                  float* __restrict__ C){
  __shared__ __align__(16) u16 As[128*64];
  __shared__ __align__(16) u16 Bs[128*64];
  int bid = blockIdx.x;
  gemm_body<true>(A, B, C, 1024, (bid >> 3) * 128, (bid & 7) * 128, As, Bs);
}

// ---------------- no-max softmax on S^T, exp2 domain (lane q = lr) ----------------
__device__ __forceinline__ void softmax_t(f32x4 s[4], float& l, u16* pl, int lr, int lg, int swzv){
  float sum = 0.f;
  #pragma unroll
  for (int nt = 0; nt < 4; nt++)
    #pragma unroll
    for (int r = 0; r < 4; r++){
      float p = ex2(s[nt][r]);
      s[nt][r] = p;
      sum += p;
    }
  sum += __shfl_xor(sum, 16);
  sum += __shfl_xor(sum, 32);
  l += sum;
  char* base = (char*)pl + lr * 128;
  #pragma unroll
  for (int nt = 0; nt < 4; nt++){
    us4 h;
    h.x = f2b_hw(s[nt][0]); h.y = f2b_hw(s[nt][1]);
    h.z = f2b_hw(s[nt][2]); h.w = f2b_hw(s[nt][3]);
    *reinterpret_cast<us4*>(base + ((nt*32 + lg*8) ^ (swzv << 4))) = h;
  }
}

// ---------------- differential flash attention: branch-per-wave, 3-buf ring, counted vmcnt ----
__global__ __launch_bounds__(512) void k_attn(const u16* __restrict__ Q, const u16* __restrict__ KVb,
                                              const u16* __restrict__ VT, const float* __restrict__ lam,
                                              u16* __restrict__ O){
  int bid = blockIdx.x;
  int logical = (bid & 7) * 32 + (bid >> 3);           // 256 % 8 == 0, bijective
  int qt2 = logical & 3, h = (logical >> 2) & 15, b = logical >> 6;
  const int tid = threadIdx.x, wave = tid >> 6, lane = tid & 63;
  const int lr = lane & 15, lg = lane >> 4;
  const int br = wave >> 2, wq = wave & 3;             // branch, q-slot
  const int swzv = (lr ^ (lr >> 3)) & 7;

  __shared__ __align__(16) u16 Ks[3][8192];            // ring [buf][64 kv][128 d] chunk-swizzled
  __shared__ __align__(16) u16 Vs[3][4096];            // ring [buf][64 d][64 kv] chunk-swizzled
  __shared__ __align__(16) u16 Pl[8][4][1024];         // [wave][qt][16 q][64 kv]; reused for combine

  const int srow = tid >> 4, schunk = tid & 15;
  const int vrow = tid >> 3, vchunk = tid & 7;
  const u16* Kg = KVb + (size_t)(b*1024 + srow) * 3072 + h*128 + ((schunk ^ (srow & 7)) << 3);
  const u16* Vg = VT + (size_t)(b*16 + h) * 65536 + (size_t)vrow * 1024 + ((vchunk ^ (vrow & 7)) << 3);

  short8 qf[4][2];
  #pragma unroll
  for (int qt = 0; qt < 4; qt++){
    const u16* Qp = Q + (size_t)(b*1024 + qt2*256 + wq*64 + qt*16 + lr) * 2048 + h*128 + br*64 + lg*8;
    qf[qt][0] = *reinterpret_cast<const short8*>(Qp);
    qf[qt][1] = *reinterpret_cast<const short8*>(Qp + 32);
  }
  const float lamh = lam[h];

  f32x4 o[4][4];
  #pragma unroll
  for (int nt = 0; nt < 4; nt++)
    #pragma unroll
    for (int qt = 0; qt < 4; qt++){ f32x4 z = {0.f,0.f,0.f,0.f}; o[nt][qt] = z; }
  float l[4] = {0.f, 0.f, 0.f, 0.f};

  auto STAGE = [&](int buf, int kv0){
    #pragma unroll
    for (int i = 0; i < 2; i++)
      gll16(Kg + (size_t)(kv0 + i*32) * 3072, &Ks[buf][i*4096 + tid*8]);
    gll16(Vg + kv0, &Vs[buf][tid*8]);
  };

  STAGE(0, 0);
  STAGE(1, 64);
  asm volatile("s_waitcnt vmcnt(3)" ::: "memory");
  __builtin_amdgcn_s_barrier();
  __builtin_amdgcn_sched_barrier(0);

  u16* Plw = &Pl[wave][0][0];

  for (int t = 0; t < 16; t++){
    const int cur = t % 3;
    if (t <= 13) STAGE((t + 2) % 3, (t + 2) << 6);

    const u16* kbuf = &Ks[cur][0];
    const u16* vbuf = &Vs[cur][0];

    short8 kf[4][2];
    #pragma unroll
    for (int nt = 0; nt < 4; nt++)
      #pragma unroll
      for (int kc = 0; kc < 2; kc++)
        kf[nt][kc] = *reinterpret_cast<const short8*>(
            kbuf + (nt*16 + lr)*128 + (((br*8 + kc*4 + lg) ^ (lr & 7)) << 3));
    #pragma unroll
    for (int qt = 0; qt < 4; qt++){
      f32x4 s[4];
      #pragma unroll
      for (int nt = 0; nt < 4; nt++){ f32x4 z = {0.f,0.f,0.f,0.f}; s[nt] = z; }
      __builtin_amdgcn_s_setprio(1);
      #pragma unroll
      for (int nt = 0; nt < 4; nt++)
        #pragma unroll
        for (int kc = 0; kc < 2; kc++)
          s[nt] = MFMA16(kf[nt][kc], qf[qt][kc], s[nt]);
      __builtin_amdgcn_s_setprio(0);
      softmax_t(s, l[qt], Plw + qt*1024, lr, lg, swzv);
    }

    #pragma unroll
    for (int kc = 0; kc < 2; kc++){
      short8 pf[4];
      #pragma unroll
      for (int qt = 0; qt < 4; qt++)
        pf[qt] = *reinterpret_cast<const short8*>(
            (char*)(Plw + qt*1024) + lr*128 + ((kc*64 + lg*16) ^ (swzv << 4)));
      __builtin_amdgcn_s_setprio(1);
      #pragma unroll
      for (int nt = 0; nt < 4; nt++){
        short8 vf = *reinterpret_cast<const short8*>(
            vbuf + (nt*16 + lr)*64 + (((kc*4 + lg) ^ (lr & 7)) << 3));
        #pragma unroll
        for (int qt = 0; qt < 4; qt++)
          o[nt][qt] = MFMA16(vf, pf[qt], o[nt][qt]);
      }
      __builtin_amdgcn_s_setprio(0);
    }

    if (t <= 13){
      asm volatile("s_waitcnt vmcnt(3)" ::: "memory");
      __builtin_amdgcn_s_barrier();
      __builtin_amdgcn_sched_barrier(0);
    } else if (t == 14){
      asm volatile("s_waitcnt vmcnt(0)" ::: "memory");
      __builtin_amdgcn_s_barrier();
      __builtin_amdgcn_sched_barrier(0);
    }
  }

  if (br == 1){
    #pragma unroll
    for (int qt = 0; qt < 4; qt++){
      const float inv2 = lamh / l[qt];
      char* base = (char*)(Plw + qt*1024) + lr * 128;
      #pragma unroll
      for (int nt = 0; nt < 4; nt++){
        us4 hh;
        #pragma unroll
        for (int r = 0; r < 4; r++)
          ((u16*)&hh)[r] = f2b_hw(o[nt][qt][r] * inv2);
        *reinterpret_cast<us4*>(base + ((nt*32 + lg*8) ^ (swzv << 4))) = hh;
      }
    }
  }
  __syncthreads();
  if (br == 0){
    u16* Px = &Pl[wave + 4][0][0];
    #pragma unroll
    for (int qt = 0; qt < 4; qt++){
      const float inv1 = 1.0f / l[qt];
      char* base = (char*)(Px + qt*1024) + lr * 128;
      u16* Op = O + (size_t)(b*1024 + qt2*256 + wq*64 + qt*16 + lr) * 1024 + h*64;
      #pragma unroll
      for (int nt = 0; nt < 4; nt++){
        us4 x = *reinterpret_cast<const us4*>(base + ((nt*32 + lg*8) ^ (swzv << 4)));
        us4 hh;
        #pragma unroll
        for (int r = 0; r < 4; r++){
          float v = o[nt][qt][r] * inv1 - b2f(((const u16*)&x)[r]);
          ((u16*)&hh)[r] = f2b_hw(v);
        }
        *reinterpret_cast<us4*>(Op + nt*16 + lg*4) = hh;
      }
    }
  }
}

// ---------------- launch ----------------
extern "C" void kernel_launch(void* const* d_in, const int* in_sizes, int n_in,
                              void* d_out, int out_size, void* d_ws, size_t ws_size,
                              hipStream_t stream){
  const float* Drift = (const float*)d_in[0];
  const float* Ocean = (const float*)d_in[1];
  const float* Wq    = (const float*)d_in[2];
  const float* Wk    = (const float*)d_in[3];
  const float* Wv    = (const float*)d_in[4];
  const float* Wo    = (const float*)d_in[5];
  const float* lq1   = (const float*)d_in[6];
  const float* lk1   = (const float*)d_in[7];
  const float* lq2   = (const float*)d_in[8];
  const float* lk2   = (const float*)d_in[9];
  float* out = (float*)d_out;

  char* ws = (char*)d_ws;
  u16* Xd   = (u16*)(ws);                      // 4096x1024 bf16
  u16* Xo   = (u16*)(ws + 8388608);            // 4096x1024
  u16* WqT  = (u16*)(ws + 16777216);           // 2048x1024
  u16* WkvT = (u16*)(ws + 20971520);           // 3072x1024
  u16* WoT  = (u16*)(ws + 27262976);           // 1024x1024
  u16* Qb   = (u16*)(ws + 29360128);           // 4096x2048
  u16* KVb  = (u16*)(ws + 46137344);           // 4096x3072
  u16* VTb  = (u16*)(ws + 71303168);           // 64x64x1024
  u16* Ob   = (u16*)(ws + 79691776);           // 4096x1024
  float* lam = (float*)(ws + 88080384);        // 16 f32

  k_prep<<<16384, 256, 0, stream>>>(Drift, Ocean, Wq, Wk, Wv, Wo, Xd, Xo,
                                    WqT, WkvT, WoT, lq1, lk1, lq2, lk2, lam);
  k_gemm_proj<<<1280, 256, 0, stream>>>(Xd, Xo, WqT, WkvT, Qb, KVb);
  k_transpose_v<<<dim3(32,2,64), 256, 0, stream>>>(KVb, VTb);
  k_attn<<<256, 512, 0, stream>>>(Qb, KVb, VTb, lam, Ob);
  k_gemm_out<<<256, 256, 0, stream>>>(Ob, WoT, out);
}